// Round 10
// baseline (693.034 us; speedup 1.0000x reference)
//
#include <hip/hip_runtime.h>
#include <hip/hip_bf16.h>
#include <math.h>

#define D 64
#define CDIM 128
#define NL 5
#define NB 8
#define HID 256
#define ODIM 1472      // D*(3*NB-1)
#define PPD 23
#define PPDP 24        // padded params per dim
#define NPAD 1536      // D*PPDP
#define NTRI 2016
#define BATCH 32768
#define CHUNK 8192     // fallback chunk if ws too small

typedef unsigned short u16;
typedef __attribute__((ext_vector_type(8))) short bf16x8;
typedef __attribute__((ext_vector_type(8))) unsigned short u16x8;
typedef __attribute__((ext_vector_type(4))) float f32x4;
typedef __attribute__((ext_vector_type(8))) float f32x8;

__device__ __forceinline__ float softplusf(float x) {
    return fmaxf(x, 0.0f) + log1pf(__expf(-fabsf(x)));
}
__device__ __forceinline__ float softplus_fast(float x) {
    return fmaxf(x, 0.0f) + __logf(1.0f + __expf(-fabsf(x)));
}
__device__ __forceinline__ float frcp(float x) { return __builtin_amdgcn_rcpf(x); }
__device__ __forceinline__ u16 f2bf(float f) {
    __hip_bfloat16 h = __float2bfloat16(f);
    return *reinterpret_cast<u16*>(&h);
}
__device__ __forceinline__ float bf2f(u16 u) {
    return __uint_as_float(((unsigned int)u) << 16);
}

// global->LDS direct 16B load; LDS dest is wave-uniform base + lane*16.
__device__ __forceinline__ void gload16(const u16* g, const u16* s) {
    __builtin_amdgcn_global_load_lds(
        (const __attribute__((address_space(1))) unsigned int*)(unsigned long long)(uintptr_t)g,
        (__attribute__((address_space(3))) unsigned int*)(unsigned int)(uintptr_t)s,
        16, 0, 0);
}

// bijective XCD-chunked swizzle (m204)
__device__ __forceinline__ int xcd_swz(int bid, int nwg) {
    int q = nwg >> 3, r = nwg & 7;
    int xcd = bid & 7, idx = bid >> 3;
    return (xcd < r ? xcd * (q + 1) : r * (q + 1) + (xcd - r) * q) + idx;
}

// ---------------- prep: context -> bf16 --------------------------------------
__global__ void cvt_ctx(const float* __restrict__ c, u16* __restrict__ o) {
    int i = blockIdx.x * 256 + threadIdx.x;
    if (i < BATCH * CDIM) o[i] = f2bf(c[i]);
}

// ---------------- prep: W1t/W2t transposed bf16 ------------------------------
__global__ void prep_w12(const float* __restrict__ W1, const float* __restrict__ W2,
                         u16* __restrict__ W1t, u16* __restrict__ W2t) {
    int i = blockIdx.x * 256 + threadIdx.x;
    if (i < NL * HID * CDIM) {   // W1t[l][n][k] = W1[l][k][n]
        int k = i % CDIM; int n = (i / CDIM) % HID; int l = i / (CDIM * HID);
        W1t[i] = f2bf(W1[(l * CDIM + k) * HID + n]);
    }
    if (i < NL * HID * HID) {    // W2t[l][n][k] = W2[l][k][n]
        int k = i % HID; int n = (i / HID) % HID; int l = i / (HID * HID);
        W2t[i] = f2bf(W2[(l * HID + k) * HID + n]);
    }
}

// ---------------- prep: W3t padded/transposed + padded bias ------------------
__global__ void prep_w3(const float* __restrict__ W3, const float* __restrict__ b3,
                        u16* __restrict__ W3t, float* __restrict__ b3p) {
    int i = blockIdx.x * 256 + threadIdx.x;
    if (i < NL * NPAD * HID) {   // W3t[l][n][k], n = d*24+p
        int k = i % HID; int n = (i / HID) % NPAD; int l = i / (HID * NPAD);
        int dd = n / PPDP, p = n % PPDP;
        W3t[i] = (p < PPD) ? f2bf(W3[(l * HID + k) * ODIM + dd * PPD + p]) : (u16)0;
    }
    if (i < NL * NPAD) {
        int n = i % NPAD; int l = i / NPAD;
        int dd = n / PPDP, p = n % PPDP;
        b3p[i] = (p < PPD) ? b3[l * ODIM + dd * PPD + p] : 0.0f;
    }
}

// ---------------- precompute: A_t = (L@U)^T per layer, total LU logdet -------
__global__ void lu_prep(const float* __restrict__ lower_e,
                        const float* __restrict__ upper_e,
                        const float* __restrict__ udiag,
                        float* __restrict__ At, float* __restrict__ lu_const) {
    int l = blockIdx.x;
    int t = threadIdx.x;
    __shared__ float Ls[D * D];
    __shared__ float Us[D * D];
    __shared__ float red[4];
    for (int idx = t; idx < D * D; idx += 256) {
        int i = idx >> 6, j = idx & 63;
        float lv;
        if (i == j)      lv = 1.0f;
        else if (i > j)  lv = lower_e[l * NTRI + (i * (i - 1)) / 2 + j];
        else             lv = 0.0f;
        Ls[idx] = lv;
        float uv;
        if (i == j)      uv = softplusf(udiag[l * D + i]) + 0.001f;
        else if (j > i)  uv = upper_e[l * NTRI + i * (D - 1) - (i * (i - 1)) / 2 + (j - i - 1)];
        else             uv = 0.0f;
        Us[idx] = uv;
    }
    __syncthreads();
    for (int idx = t; idx < D * D; idx += 256) {
        int i = idx >> 6, j = idx & 63;
        float acc = 0.0f;
        int km = min(i, j);
        for (int k = 0; k <= km; ++k) acc += Ls[i * D + k] * Us[k * D + j];
        At[(l * D + j) * D + i] = acc;   // transposed store
    }
    if (l == 0) {
        float s = 0.0f;
        for (int i = t; i < NL * D; i += 256)
            s += __logf(softplusf(udiag[i]) + 0.001f);
#pragma unroll
        for (int off = 32; off; off >>= 1) s += __shfl_xor(s, off);
        if ((t & 63) == 0) red[t >> 6] = s;
        __syncthreads();
        if (t == 0) lu_const[0] = red[0] + red[1] + red[2] + red[3];
    }
}

// ---------------- init: copy x, zero logdet ----------------------------------
__global__ void init_kernel(const float* __restrict__ inp, float* __restrict__ x,
                            float* __restrict__ logdet) {
    int i = blockIdx.x * 256 + threadIdx.x;
    if (i < BATCH * D) x[i] = inp[i];
    if (i < BATCH) logdet[i] = 0.0f;
}

// ---------------- MFMA GEMM, layers batched via grid.y (proven r7 structure) -
template<int RELU>
__global__ __launch_bounds__(256) void gemm_bf16(
    const u16* __restrict__ A0, const u16* __restrict__ Bt0,
    const float* __restrict__ bias0, u16* __restrict__ Cv0,
    int N, int K, int ncol, size_t sA, size_t sB, size_t sb, size_t sC)
{
    __shared__ u16 lds[16384];
    const int ly = blockIdx.y;
    const u16* A = A0 + (size_t)ly * sA;
    const u16* Bt = Bt0 + (size_t)ly * sB;
    const float* bias = bias0 + (size_t)ly * sb;
    u16* Cv = Cv0 + (size_t)ly * sC;
    const int t = threadIdx.x;
    const int w = t >> 6, l = t & 63;
    const int wm = w >> 1, wn = w & 1;
    const int wg = xcd_swz(blockIdx.x, gridDim.x);
    const size_t m0 = (size_t)(wg / ncol) * 128;
    const int n0 = (wg % ncol) * 128;
    const int lrow = l & 15, lk = l >> 4;
    const int srow = l >> 3, sslot = l & 7;

    f32x4 acc[4][4] = {};

    for (int k0 = 0; k0 < K; k0 += 64) {
#pragma unroll
        for (int q = 0; q < 4; ++q) {
            int c = q * 4 + w;
            int row = c * 8 + srow;
            int slog = sslot ^ (row & 7);
            gload16(A + (m0 + row) * K + k0 + slog * 8, &lds[c * 512]);
        }
#pragma unroll
        for (int q = 0; q < 4; ++q) {
            int c = q * 4 + w;
            int row = c * 8 + srow;
            int slog = sslot ^ (row & 7);
            gload16(Bt + (size_t)(n0 + row) * K + k0 + slog * 8, &lds[8192 + c * 512]);
        }
        __syncthreads();
#pragma unroll
        for (int ks = 0; ks < 2; ++ks) {
            bf16x8 a[4], b[4];
#pragma unroll
            for (int mf = 0; mf < 4; ++mf) {
                int row = wm * 64 + mf * 16 + lrow;
                int slot = (ks * 4 + lk) ^ (row & 7);
                a[mf] = *(const bf16x8*)&lds[row * 64 + slot * 8];
            }
#pragma unroll
            for (int nf = 0; nf < 4; ++nf) {
                int row = wn * 64 + nf * 16 + lrow;
                int slot = (ks * 4 + lk) ^ (row & 7);
                b[nf] = *(const bf16x8*)&lds[8192 + row * 64 + slot * 8];
            }
#pragma unroll
            for (int mf = 0; mf < 4; ++mf)
#pragma unroll
                for (int nf = 0; nf < 4; ++nf)
                    acc[mf][nf] = __builtin_amdgcn_mfma_f32_16x16x32_bf16(
                        a[mf], b[nf], acc[mf][nf], 0, 0, 0);
        }
        __syncthreads();
    }
#pragma unroll
    for (int nf = 0; nf < 4; ++nf) {
        int col = n0 + wn * 64 + nf * 16 + lrow;
        float bv = bias[col];
#pragma unroll
        for (int mf = 0; mf < 4; ++mf) {
            size_t rbase = m0 + wm * 64 + mf * 16 + lk * 4;
#pragma unroll
            for (int i = 0; i < 4; ++i) {
                float v = acc[mf][nf][i] + bv;
                if (RELU) v = fmaxf(v, 0.0f);
                Cv[(rbase + i) * N + col] = f2bf(v);
            }
        }
    }
}

// ---------------- spline helpers (register-only) -----------------------------
__device__ __forceinline__ f32x8 cumb(f32x8 p) {
    float m = fmaxf(fmaxf(fmaxf(p[0], p[1]), fmaxf(p[2], p[3])),
                    fmaxf(fmaxf(p[4], p[5]), fmaxf(p[6], p[7])));
    f32x8 e;
    float s = 0.0f;
#pragma unroll
    for (int i = 0; i < 8; ++i) { e[i] = __expf(p[i] - m); s += e[i]; }
    float tt = 0.992f * frcp(s);
    f32x8 c;
    float run = 0.0f;
#pragma unroll
    for (int i = 0; i < 7; ++i) {
        run = fmaf(tt, e[i], run + 0.001f);
        c[i] = fmaf(10.0f, run, -5.0f);
    }
    c[7] = 5.0f;
    return c;
}

__device__ __forceinline__ void rqs_v(float xv, f32x8 uw, f32x8 uh, f32x8 ud,
                                      float& yo, float& ldo) {
    f32x8 cw = cumb(uw);
    f32x8 ch = cumb(uh);
    f32x8 dv;
#pragma unroll
    for (int i = 0; i < 7; ++i) dv[i] = 0.001f + softplus_fast(ud[i]);
    float xc = fminf(fmaxf(xv, -5.0f), 5.0f);
    float icw = -5.0f, icw1 = cw[0], ich = -5.0f, ich1 = ch[0];
    float d0 = 1.0f, d1 = dv[0];
#pragma unroll
    for (int k = 1; k < 8; ++k) {
        bool sel = (xc >= cw[k - 1]);
        icw  = sel ? cw[k - 1] : icw;
        icw1 = sel ? cw[k]     : icw1;
        ich  = sel ? ch[k - 1] : ich;
        ich1 = sel ? ch[k]     : ich1;
        d0   = sel ? dv[k - 1] : d0;
        d1   = sel ? ((k < 7) ? dv[k] : 1.0f) : d1;
    }
    float iw  = icw1 - icw;
    float ih  = ich1 - ich;
    float riw = frcp(iw);
    float dlt = ih * riw;
    float th  = (xc - icw) * riw;
    float omt = 1.0f - th;
    float tomt = th * omt;
    float numer = ih * (dlt * th * th + d0 * tomt);
    float den = dlt + (d0 + d1 - 2.0f * dlt) * tomt;
    float rden = frcp(den);
    float outv = ich + numer * rden;
    float dnum = dlt * dlt * (d1 * th * th + 2.0f * dlt * tomt + d0 * omt * omt);
    float ld = __logf(dnum * rden * rden);
    bool inside = (xv >= -5.0f) && (xv <= 5.0f);
    yo  = inside ? outv : xv;
    ldo = inside ? ld : 0.0f;
}

// ---------------- spline + LU: one row per wave, 8 rows/block ----------------
__global__ __launch_bounds__(512) void spline_lu_kernel(
    const u16* __restrict__ params,   // [chunk][NPAD] bf16, chunk-local
    const float* __restrict__ At, const float* __restrict__ lu_bias,
    float* __restrict__ x, float* __restrict__ logdet,
    int l, int row_base)
{
    __shared__ float y_s[8 * D];
    const int t = threadIdx.x;
    const int d = t & 63, g = t >> 6;
    const size_t crow = (size_t)blockIdx.x * 8 + g;
    const size_t grow = (size_t)row_base + crow;

    const u16x8* pp = (const u16x8*)(params + crow * NPAD + d * PPDP);
    u16x8 q0 = pp[0], q1 = pp[1], q2 = pp[2];
    f32x8 uw, uh, ud;
#pragma unroll
    for (int j = 0; j < 8; ++j) {
        uw[j] = bf2f(q0[j]);
        uh[j] = bf2f(q1[j]);
        ud[j] = bf2f(q2[j]);   // element 7 is pad (unused)
    }
    float xv = x[grow * D + d];
    float y, ld;
    rqs_v(xv, uw, uh, ud, y, ld);
    y_s[g * D + d] = y;
#pragma unroll
    for (int off = 32; off; off >>= 1) ld += __shfl_xor(ld, off);
    if (d == 0) logdet[grow] += ld;
    __syncthreads();

    // LU: x_new[row g][dim d] = sum_j y[g][j] * A[d][j] + bias[d]
    float acc = lu_bias[l * D + d];
    const float* ap = At + (size_t)l * D * D + d;   // At[(l*D+j)*D + d] = A[d][j]
#pragma unroll 8
    for (int j = 0; j < D; ++j)
        acc = fmaf(y_s[g * D + j], ap[j * D], acc);
    x[grow * D + d] = acc;
}

// ---------------- final: out = base + logdet ---------------------------------
__global__ void final_kernel(const float* __restrict__ x,
                             const float* __restrict__ logdet,
                             const float* __restrict__ lu_const,
                             float* __restrict__ out) {
    int t = threadIdx.x;
    int b = blockIdx.x * 4 + (t >> 6);
    int d = t & 63;
    float v = x[(size_t)b * D + d];
    float s = v * v;
#pragma unroll
    for (int off = 32; off; off >>= 1) s += __shfl_xor(s, off);
    if (d == 0)
        out[b] = logdet[b] + lu_const[0] - 0.5f * s - 0.5f * 64.0f * 1.8378770664093453f;
}

extern "C" void kernel_launch(void* const* d_in, const int* in_sizes, int n_in,
                              void* d_out, int out_size, void* d_ws, size_t ws_size,
                              hipStream_t stream) {
    const float* inputs  = (const float*)d_in[0];
    const float* context = (const float*)d_in[1];
    const float* W1      = (const float*)d_in[2];
    const float* b1      = (const float*)d_in[3];
    const float* W2      = (const float*)d_in[4];
    const float* b2      = (const float*)d_in[5];
    const float* W3      = (const float*)d_in[6];
    const float* b3      = (const float*)d_in[7];
    const float* lu_bias = (const float*)d_in[8];
    const float* lower_e = (const float*)d_in[9];
    const float* upper_e = (const float*)d_in[10];
    const float* udiag   = (const float*)d_in[11];
    float* out = (float*)d_out;

    char* p = (char*)d_ws;
    auto alloc = [&](size_t bytes) { void* r = p; p += (bytes + 255) & ~(size_t)255; return r; };
    float* x        = (float*)alloc((size_t)BATCH * D * 4);
    float* logdet   = (float*)alloc((size_t)BATCH * 4);
    float* At       = (float*)alloc((size_t)NL * D * D * 4);
    float* lu_const = (float*)alloc(256);
    u16*   ctx_bf   = (u16*)alloc((size_t)BATCH * CDIM * 2);
    u16*   hh1      = (u16*)alloc((size_t)NL * BATCH * HID * 2);   // all layers
    u16*   hh2      = (u16*)alloc((size_t)NL * BATCH * HID * 2);   // all layers
    u16*   W1t      = (u16*)alloc((size_t)NL * HID * CDIM * 2);
    u16*   W2t      = (u16*)alloc((size_t)NL * HID * HID * 2);
    u16*   W3t      = (u16*)alloc((size_t)NL * NPAD * HID * 2);
    float* b3p      = (float*)alloc((size_t)NL * NPAD * 4);

    // params sizing: prefer all-layers (1 batched G3 dispatch), then full-batch
    // per-layer, then 8K-chunked fallback.
    size_t used = (size_t)(p - (char*)d_ws);
    size_t avail = ws_size - used;
    const size_t perLayer = (size_t)BATCH * NPAD * 2;
    int mode = (avail >= NL * perLayer + 4096) ? 2
             : (avail >= perLayer + 4096)      ? 1 : 0;
    u16* paramsB = (u16*)alloc(mode == 2 ? NL * perLayer : (mode == 1 ? perLayer
                               : (size_t)CHUNK * NPAD * 2));

    cvt_ctx<<<(BATCH * CDIM + 255) / 256, 256, 0, stream>>>(context, ctx_bf);
    prep_w12<<<(NL * HID * HID + 255) / 256, 256, 0, stream>>>(W1, W2, W1t, W2t);
    prep_w3<<<(NL * NPAD * HID + 255) / 256, 256, 0, stream>>>(W3, b3, W3t, b3p);
    lu_prep<<<NL, 256, 0, stream>>>(lower_e, upper_e, udiag, At, lu_const);
    init_kernel<<<(BATCH * D + 255) / 256, 256, 0, stream>>>(inputs, x, logdet);

    // conditioner depends only on context: all layers in one dispatch each
    dim3 gmlp((BATCH / 128) * 2, NL);
    gemm_bf16<1><<<gmlp, 256, 0, stream>>>(
        ctx_bf, W1t, b1, hh1, HID, CDIM, 2,
        0, (size_t)HID * CDIM, HID, (size_t)BATCH * HID);
    gemm_bf16<1><<<gmlp, 256, 0, stream>>>(
        hh1, W2t, b2, hh2, HID, HID, 2,
        (size_t)BATCH * HID, (size_t)HID * HID, HID, (size_t)BATCH * HID);

    if (mode == 2) {
        // all 5 layers' GEMM3 in one dispatch (independent given hh2)
        dim3 g3((BATCH / 128) * (NPAD / 128), NL);
        gemm_bf16<0><<<g3, 256, 0, stream>>>(
            hh2, W3t, b3p, paramsB, NPAD, HID, NPAD / 128,
            (size_t)BATCH * HID, (size_t)NPAD * HID, NPAD, (size_t)BATCH * NPAD);
        for (int l = 0; l < NL; ++l)
            spline_lu_kernel<<<BATCH / 8, 512, 0, stream>>>(
                paramsB + (size_t)l * BATCH * NPAD, At, lu_bias, x, logdet, l, 0);
    } else {
        int chunk = (mode == 1) ? BATCH : CHUNK;
        for (int l = 0; l < NL; ++l) {
            for (int c = 0; c < BATCH / chunk; ++c) {
                dim3 g3((chunk / 128) * (NPAD / 128), 1);
                gemm_bf16<0><<<g3, 256, 0, stream>>>(
                    hh2 + (size_t)l * BATCH * HID + (size_t)c * chunk * HID,
                    W3t + (size_t)l * NPAD * HID, b3p + (size_t)l * NPAD,
                    paramsB, NPAD, HID, NPAD / 128, 0, 0, 0, 0);
                spline_lu_kernel<<<chunk / 8, 512, 0, stream>>>(
                    paramsB, At, lu_bias, x, logdet, l, c * chunk);
            }
        }
    }
    final_kernel<<<BATCH / 4, 256, 0, stream>>>(x, logdet, lu_const, out);
}

// Round 11
// 590.841 us; speedup vs baseline: 1.1730x; 1.1730x over previous
//
#include <hip/hip_runtime.h>
#include <hip/hip_bf16.h>
#include <math.h>

#define D 64
#define CDIM 128
#define NL 5
#define NB 8
#define HID 256
#define ODIM 1472      // D*(3*NB-1)
#define PPD 23
#define PPDP 24        // padded params per dim
#define NPAD 1536      // D*PPDP
#define NTRI 2016
#define BATCH 32768
#define CHUNK 8192     // fallback chunk if ws too small for full batch

typedef unsigned short u16;
typedef __attribute__((ext_vector_type(8))) short bf16x8;
typedef __attribute__((ext_vector_type(8))) unsigned short u16x8;
typedef __attribute__((ext_vector_type(4))) float f32x4;
typedef __attribute__((ext_vector_type(8))) float f32x8;

__device__ __forceinline__ float softplusf(float x) {
    return fmaxf(x, 0.0f) + log1pf(__expf(-fabsf(x)));
}
__device__ __forceinline__ float softplus_fast(float x) {
    return fmaxf(x, 0.0f) + __logf(1.0f + __expf(-fabsf(x)));
}
__device__ __forceinline__ float frcp(float x) { return __builtin_amdgcn_rcpf(x); }
__device__ __forceinline__ u16 f2bf(float f) {
    __hip_bfloat16 h = __float2bfloat16(f);
    return *reinterpret_cast<u16*>(&h);
}
__device__ __forceinline__ float bf2f(u16 u) {
    return __uint_as_float(((unsigned int)u) << 16);
}

// global->LDS direct 16B load; LDS dest is wave-uniform base + lane*16.
__device__ __forceinline__ void gload16(const u16* g, const u16* s) {
    __builtin_amdgcn_global_load_lds(
        (const __attribute__((address_space(1))) unsigned int*)(unsigned long long)(uintptr_t)g,
        (__attribute__((address_space(3))) unsigned int*)(unsigned int)(uintptr_t)s,
        16, 0, 0);
}

// bijective XCD-chunked swizzle (m204)
__device__ __forceinline__ int xcd_swz(int bid, int nwg) {
    int q = nwg >> 3, r = nwg & 7;
    int xcd = bid & 7, idx = bid >> 3;
    return (xcd < r ? xcd * (q + 1) : r * (q + 1) + (xcd - r) * q) + idx;
}

// ---------------- prep: context -> bf16 (vectorized) -------------------------
__global__ void cvt_ctx(const float* __restrict__ c, u16* __restrict__ o) {
    int i = blockIdx.x * 256 + threadIdx.x;
    if (i < BATCH * CDIM / 4) {
        float4 v = reinterpret_cast<const float4*>(c)[i];
        unsigned lo = (unsigned)f2bf(v.x) | ((unsigned)f2bf(v.y) << 16);
        unsigned hi = (unsigned)f2bf(v.z) | ((unsigned)f2bf(v.w) << 16);
        uint2 pv; pv.x = lo; pv.y = hi;
        reinterpret_cast<uint2*>(o)[i] = pv;
    }
}

// ---------------- prep: LDS-tiled transpose fp32[R][C] -> bf16[Cout][R] ------
// Both global sides coalesced; MAP=1 folds the W3 23->24 pad remap into reads.
template<int MAP>
__global__ __launch_bounds__(256) void transpose_prep(
    const float* __restrict__ in, u16* __restrict__ out, int R, int C, int Cout)
{
    __shared__ u16 tile[32][33];
    const int l = blockIdx.z;
    const int c0 = blockIdx.x * 32, r0 = blockIdx.y * 32;
    const int tx = threadIdx.x & 31, ty = threadIdx.x >> 5;
    const float* inl = in + (size_t)l * R * C;
#pragma unroll
    for (int i = 0; i < 4; ++i) {
        int r = r0 + ty * 4 + i;
        int cc = c0 + tx;
        int src = cc;
        if (MAP) { int dd = cc / PPDP, pp = cc % PPDP; src = (pp < PPD) ? dd * PPD + pp : -1; }
        u16 v = 0;
        if (src >= 0) v = f2bf(inl[(size_t)r * C + src]);
        tile[ty * 4 + i][tx] = v;
    }
    __syncthreads();
    u16* outl = out + (size_t)l * Cout * R;
#pragma unroll
    for (int i = 0; i < 4; ++i) {
        int cc = c0 + ty * 4 + i;
        outl[(size_t)cc * R + r0 + tx] = tile[tx][ty * 4 + i];
    }
}

// ---------------- prep: padded bias ------------------------------------------
__global__ void prep_b3(const float* __restrict__ b3, float* __restrict__ b3p) {
    int i = blockIdx.x * 256 + threadIdx.x;
    if (i < NL * NPAD) {
        int n = i % NPAD; int l = i / NPAD;
        int dd = n / PPDP, p = n % PPDP;
        b3p[i] = (p < PPD) ? b3[l * ODIM + dd * PPD + p] : 0.0f;
    }
}

// ---------------- precompute: A_t = (L@U)^T per layer, total LU logdet -------
__global__ void lu_prep(const float* __restrict__ lower_e,
                        const float* __restrict__ upper_e,
                        const float* __restrict__ udiag,
                        float* __restrict__ At, float* __restrict__ lu_const) {
    int l = blockIdx.x;
    int t = threadIdx.x;
    __shared__ float Ls[D * D];
    __shared__ float Us[D * D];
    __shared__ float red[4];
    for (int idx = t; idx < D * D; idx += 256) {
        int i = idx >> 6, j = idx & 63;
        float lv;
        if (i == j)      lv = 1.0f;
        else if (i > j)  lv = lower_e[l * NTRI + (i * (i - 1)) / 2 + j];
        else             lv = 0.0f;
        Ls[idx] = lv;
        float uv;
        if (i == j)      uv = softplusf(udiag[l * D + i]) + 0.001f;
        else if (j > i)  uv = upper_e[l * NTRI + i * (D - 1) - (i * (i - 1)) / 2 + (j - i - 1)];
        else             uv = 0.0f;
        Us[idx] = uv;
    }
    __syncthreads();
    for (int idx = t; idx < D * D; idx += 256) {
        int i = idx >> 6, j = idx & 63;
        float acc = 0.0f;
        int km = min(i, j);
        for (int k = 0; k <= km; ++k) acc += Ls[i * D + k] * Us[k * D + j];
        At[(l * D + j) * D + i] = acc;   // transposed store
    }
    if (l == 0) {
        float s = 0.0f;
        for (int i = t; i < NL * D; i += 256)
            s += __logf(softplusf(udiag[i]) + 0.001f);
#pragma unroll
        for (int off = 32; off; off >>= 1) s += __shfl_xor(s, off);
        if ((t & 63) == 0) red[t >> 6] = s;
        __syncthreads();
        if (t == 0) lu_const[0] = red[0] + red[1] + red[2] + red[3];
    }
}

// ---------------- init: copy x, zero logdet ----------------------------------
__global__ void init_kernel(const float* __restrict__ inp, float* __restrict__ x,
                            float* __restrict__ logdet) {
    int i = blockIdx.x * 256 + threadIdx.x;
    if (i < BATCH * D) x[i] = inp[i];
    if (i < BATCH) logdet[i] = 0.0f;
}

// ---------------- MFMA GEMM: C = [relu](A @ Bt^T + bias) ---------------------
// Round-4 K-loop (proven) + NEW epilogue: C transposed through the (now free)
// staging LDS -> 16B global stores. Old epilogue was 64x 2B scalar stores per
// thread = store-issue bound (~1.9 TB/s measured on G1/G2/G3 write streams).
template<int RELU>
__global__ __launch_bounds__(256) void gemm_bf16(
    const u16* __restrict__ A, const u16* __restrict__ Bt,
    const float* __restrict__ bias, u16* __restrict__ Cv,
    int N, int K, int ncol)
{
    __shared__ u16 lds[16384];
    const int t = threadIdx.x;
    const int w = t >> 6, l = t & 63;
    const int wm = w >> 1, wn = w & 1;
    const int wg = xcd_swz(blockIdx.x, gridDim.x);
    const size_t m0 = (size_t)(wg / ncol) * 128;
    const int n0 = (wg % ncol) * 128;
    const int lrow = l & 15, lk = l >> 4;
    const int srow = l >> 3, sslot = l & 7;

    f32x4 acc[4][4] = {};

    for (int k0 = 0; k0 < K; k0 += 64) {
#pragma unroll
        for (int q = 0; q < 4; ++q) {
            int c = q * 4 + w;
            int row = c * 8 + srow;
            int slog = sslot ^ (row & 7);
            gload16(A + (m0 + row) * K + k0 + slog * 8, &lds[c * 512]);
        }
#pragma unroll
        for (int q = 0; q < 4; ++q) {
            int c = q * 4 + w;
            int row = c * 8 + srow;
            int slog = sslot ^ (row & 7);
            gload16(Bt + (size_t)(n0 + row) * K + k0 + slog * 8, &lds[8192 + c * 512]);
        }
        __syncthreads();
#pragma unroll
        for (int ks = 0; ks < 2; ++ks) {
            bf16x8 a[4], b[4];
#pragma unroll
            for (int mf = 0; mf < 4; ++mf) {
                int row = wm * 64 + mf * 16 + lrow;
                int slot = (ks * 4 + lk) ^ (row & 7);
                a[mf] = *(const bf16x8*)&lds[row * 64 + slot * 8];
            }
#pragma unroll
            for (int nf = 0; nf < 4; ++nf) {
                int row = wn * 64 + nf * 16 + lrow;
                int slot = (ks * 4 + lk) ^ (row & 7);
                b[nf] = *(const bf16x8*)&lds[8192 + row * 64 + slot * 8];
            }
#pragma unroll
            for (int mf = 0; mf < 4; ++mf)
#pragma unroll
                for (int nf = 0; nf < 4; ++nf)
                    acc[mf][nf] = __builtin_amdgcn_mfma_f32_16x16x32_bf16(
                        a[mf], b[nf], acc[mf][nf], 0, 0, 0);
        }
        __syncthreads();   // also frees lds for the epilogue (all reads done)
    }

    // ---- epilogue: per-wave 64x64 tile via private 8KB LDS region ----
    // value (r = mf*16+lk*4+i, cl = nf*16+lrow) -> phys u16 index
    //   r*64 + ((cl>>3) ^ (r&7))*8 + (cl&7)   (16B-slot XOR swizzle)
    // write: shfl-pack col pairs -> b32 LDS writes (even lanes)
    // read:  b128 per (row, 8-col slot) -> global dwordx4
    {
        u16* region = &lds[w * 4096];
#pragma unroll
        for (int nf = 0; nf < 4; ++nf) {
            float bv = bias[n0 + wn * 64 + nf * 16 + lrow];
#pragma unroll
            for (int mf = 0; mf < 4; ++mf) {
#pragma unroll
                for (int i = 0; i < 4; ++i) {
                    float v = acc[mf][nf][i] + bv;
                    if (RELU) v = fmaxf(v, 0.0f);
                    unsigned b = (unsigned)f2bf(v);
                    unsigned o = __shfl_xor(b, 1);
                    if (!(lrow & 1)) {
                        int r = mf * 16 + lk * 4 + i;
                        int slot = (nf << 1) | (lrow >> 3);
                        int dw = r * 32 + ((slot ^ (r & 7)) << 2) + ((lrow & 7) >> 1);
                        *reinterpret_cast<unsigned*>(&region[dw * 2]) = b | (o << 16);
                    }
                }
            }
        }
        // wave-private region: no barrier needed; lgkmcnt orders ds ops
#pragma unroll
        for (int s = 0; s < 8; ++s) {
            int r = s * 8 + (l >> 3);
            int slot = (l & 7) ^ (r & 7);
            bf16x8 vv = *(const bf16x8*)&region[r * 64 + slot * 8];
            *(bf16x8*)(Cv + (m0 + wm * 64 + r) * N + n0 + wn * 64 + 8 * (l & 7)) = vv;
        }
    }
}

// ---------------- spline helpers (register-only) -----------------------------
__device__ __forceinline__ f32x8 cumb(f32x8 p) {
    float m = fmaxf(fmaxf(fmaxf(p[0], p[1]), fmaxf(p[2], p[3])),
                    fmaxf(fmaxf(p[4], p[5]), fmaxf(p[6], p[7])));
    f32x8 e;
    float s = 0.0f;
#pragma unroll
    for (int i = 0; i < 8; ++i) { e[i] = __expf(p[i] - m); s += e[i]; }
    float tt = 0.992f * frcp(s);
    f32x8 c;
    float run = 0.0f;
#pragma unroll
    for (int i = 0; i < 7; ++i) {
        run = fmaf(tt, e[i], run + 0.001f);
        c[i] = fmaf(10.0f, run, -5.0f);
    }
    c[7] = 5.0f;
    return c;
}

__device__ __forceinline__ void rqs_v(float xv, f32x8 uw, f32x8 uh, f32x8 ud,
                                      float& yo, float& ldo) {
    f32x8 cw = cumb(uw);
    f32x8 ch = cumb(uh);
    f32x8 dv;
#pragma unroll
    for (int i = 0; i < 7; ++i) dv[i] = 0.001f + softplus_fast(ud[i]);
    float xc = fminf(fmaxf(xv, -5.0f), 5.0f);
    float icw = -5.0f, icw1 = cw[0], ich = -5.0f, ich1 = ch[0];
    float d0 = 1.0f, d1 = dv[0];
#pragma unroll
    for (int k = 1; k < 8; ++k) {
        bool sel = (xc >= cw[k - 1]);
        icw  = sel ? cw[k - 1] : icw;
        icw1 = sel ? cw[k]     : icw1;
        ich  = sel ? ch[k - 1] : ich;
        ich1 = sel ? ch[k]     : ich1;
        d0   = sel ? dv[k - 1] : d0;
        d1   = sel ? ((k < 7) ? dv[k] : 1.0f) : d1;
    }
    float iw  = icw1 - icw;
    float ih  = ich1 - ich;
    float riw = frcp(iw);
    float dlt = ih * riw;
    float th  = (xc - icw) * riw;
    float omt = 1.0f - th;
    float tomt = th * omt;
    float numer = ih * (dlt * th * th + d0 * tomt);
    float den = dlt + (d0 + d1 - 2.0f * dlt) * tomt;
    float rden = frcp(den);
    float outv = ich + numer * rden;
    float dnum = dlt * dlt * (d1 * th * th + 2.0f * dlt * tomt + d0 * omt * omt);
    float ld = __logf(dnum * rden * rden);
    bool inside = (xv >= -5.0f) && (xv <= 5.0f);
    yo  = inside ? outv : xv;
    ldo = inside ? ld : 0.0f;
}

// ---------------- spline + LU: one row per wave, 8 rows/block ----------------
__global__ __launch_bounds__(512) void spline_lu_kernel(
    const u16* __restrict__ params,   // [chunk][NPAD] bf16, chunk-local
    const float* __restrict__ At, const float* __restrict__ lu_bias,
    float* __restrict__ x, float* __restrict__ logdet,
    int l, int row_base)
{
    __shared__ float y_s[8 * D];
    const int t = threadIdx.x;
    const int d = t & 63, g = t >> 6;
    const size_t crow = (size_t)blockIdx.x * 8 + g;
    const size_t grow = (size_t)row_base + crow;

    const u16x8* pp = (const u16x8*)(params + crow * NPAD + d * PPDP);
    u16x8 q0 = pp[0], q1 = pp[1], q2 = pp[2];
    f32x8 uw, uh, ud;
#pragma unroll
    for (int j = 0; j < 8; ++j) {
        uw[j] = bf2f(q0[j]);
        uh[j] = bf2f(q1[j]);
        ud[j] = bf2f(q2[j]);   // element 7 is pad (unused)
    }
    float xv = x[grow * D + d];
    float y, ld;
    rqs_v(xv, uw, uh, ud, y, ld);
    y_s[g * D + d] = y;
#pragma unroll
    for (int off = 32; off; off >>= 1) ld += __shfl_xor(ld, off);
    if (d == 0) logdet[grow] += ld;
    __syncthreads();

    // LU: x_new[row g][dim d] = sum_j y[g][j] * A[d][j] + bias[d]
    float acc = lu_bias[l * D + d];
    const float* ap = At + (size_t)l * D * D + d;   // At[(l*D+j)*D + d] = A[d][j]
#pragma unroll 8
    for (int j = 0; j < D; ++j)
        acc = fmaf(y_s[g * D + j], ap[j * D], acc);
    x[grow * D + d] = acc;
}

// ---------------- final: out = base + logdet ---------------------------------
__global__ void final_kernel(const float* __restrict__ x,
                             const float* __restrict__ logdet,
                             const float* __restrict__ lu_const,
                             float* __restrict__ out) {
    int t = threadIdx.x;
    int b = blockIdx.x * 4 + (t >> 6);
    int d = t & 63;
    float v = x[(size_t)b * D + d];
    float s = v * v;
#pragma unroll
    for (int off = 32; off; off >>= 1) s += __shfl_xor(s, off);
    if (d == 0)
        out[b] = logdet[b] + lu_const[0] - 0.5f * s - 0.5f * 64.0f * 1.8378770664093453f;
}

extern "C" void kernel_launch(void* const* d_in, const int* in_sizes, int n_in,
                              void* d_out, int out_size, void* d_ws, size_t ws_size,
                              hipStream_t stream) {
    const float* inputs  = (const float*)d_in[0];
    const float* context = (const float*)d_in[1];
    const float* W1      = (const float*)d_in[2];
    const float* b1      = (const float*)d_in[3];
    const float* W2      = (const float*)d_in[4];
    const float* b2      = (const float*)d_in[5];
    const float* W3      = (const float*)d_in[6];
    const float* b3      = (const float*)d_in[7];
    const float* lu_bias = (const float*)d_in[8];
    const float* lower_e = (const float*)d_in[9];
    const float* upper_e = (const float*)d_in[10];
    const float* udiag   = (const float*)d_in[11];
    float* out = (float*)d_out;

    char* p = (char*)d_ws;
    auto alloc = [&](size_t bytes) { void* r = p; p += (bytes + 255) & ~(size_t)255; return r; };
    float* x        = (float*)alloc((size_t)BATCH * D * 4);
    float* logdet   = (float*)alloc((size_t)BATCH * 4);
    float* At       = (float*)alloc((size_t)NL * D * D * 4);
    float* lu_const = (float*)alloc(256);
    u16*   ctx_bf   = (u16*)alloc((size_t)BATCH * CDIM * 2);
    u16*   hh1      = (u16*)alloc((size_t)BATCH * HID * 2);
    u16*   hh2      = (u16*)alloc((size_t)BATCH * HID * 2);
    u16*   W1t      = (u16*)alloc((size_t)NL * HID * CDIM * 2);
    u16*   W2t      = (u16*)alloc((size_t)NL * HID * HID * 2);
    u16*   W3t      = (u16*)alloc((size_t)NL * NPAD * HID * 2);
    float* b3p      = (float*)alloc((size_t)NL * NPAD * 4);

    size_t used = (size_t)(p - (char*)d_ws);
    int chunk = (ws_size - used >= (size_t)BATCH * NPAD * 2 + 256) ? BATCH : CHUNK;
    u16* paramsB = (u16*)alloc((size_t)chunk * NPAD * 2);

    cvt_ctx<<<(BATCH * CDIM / 4 + 255) / 256, 256, 0, stream>>>(context, ctx_bf);
    transpose_prep<0><<<dim3(HID / 32, CDIM / 32, NL), 256, 0, stream>>>(
        W1, W1t, CDIM, HID, HID);
    transpose_prep<0><<<dim3(HID / 32, HID / 32, NL), 256, 0, stream>>>(
        W2, W2t, HID, HID, HID);
    transpose_prep<1><<<dim3(NPAD / 32, HID / 32, NL), 256, 0, stream>>>(
        W3, W3t, HID, ODIM, NPAD);
    prep_b3<<<(NL * NPAD + 255) / 256, 256, 0, stream>>>(b3, b3p);
    lu_prep<<<NL, 256, 0, stream>>>(lower_e, upper_e, udiag, At, lu_const);
    init_kernel<<<(BATCH * D + 255) / 256, 256, 0, stream>>>(inputs, x, logdet);

    for (int l = 0; l < NL; ++l) {
        gemm_bf16<1><<<(BATCH / 128) * 2, 256, 0, stream>>>(
            ctx_bf, W1t + (size_t)l * HID * CDIM, b1 + l * HID, hh1, HID, CDIM, 2);
        gemm_bf16<1><<<(BATCH / 128) * 2, 256, 0, stream>>>(
            hh1, W2t + (size_t)l * HID * HID, b2 + l * HID, hh2, HID, HID, 2);
        for (int c = 0; c < BATCH / chunk; ++c) {
            gemm_bf16<0><<<(chunk / 128) * (NPAD / 128), 256, 0, stream>>>(
                hh2 + (size_t)c * chunk * HID, W3t + (size_t)l * NPAD * HID,
                b3p + l * NPAD, paramsB, NPAD, HID, NPAD / 128);
            spline_lu_kernel<<<chunk / 8, 512, 0, stream>>>(
                paramsB, At, lu_bias, x, logdet, l, c * chunk);
        }
    }
    final_kernel<<<BATCH / 4, 256, 0, stream>>>(x, logdet, lu_const, out);
}